// Round 8
// baseline (304.139 us; speedup 1.0000x reference)
//
#include <hip/hip_runtime.h>
#include <math.h>

#define BB 4
#define NN 8192
#define DD 16
#define KK 32
#define OO 64
#define QPW 4        // queries per wave
#define QB  16       // queries per block (256 threads = 4 waves)
#define NCH (NN/64)  // 128 sorted chunks of 64 points

// ---- sortable-float helpers (monotone bijection float -> uint32) ----------
__device__ __forceinline__ unsigned encf(float f) {
  unsigned u = __float_as_uint(f);
  return ((int)u >= 0) ? (u | 0x80000000u) : ~u;
}
__device__ __forceinline__ float decf(unsigned s) {
  unsigned u = (s & 0x80000000u) ? (s & 0x7fffffffu) : ~s;
  return __uint_as_float(u);
}
__device__ __forceinline__ float ulp_up(float f) {
  unsigned u = __float_as_uint(f);
  u = ((u << 1) == 0u) ? 1u : (((int)u >= 0) ? u + 1u : u - 1u);
  return __uint_as_float(u);
}
// ---- 64-lane bitonic sorts (ascending) ------------------------------------
__device__ __forceinline__ unsigned long long bsort64(unsigned long long key,
                                                      int lane) {
#pragma unroll
  for (int k = 2; k <= 64; k <<= 1) {
#pragma unroll
    for (int j = k >> 1; j > 0; j >>= 1) {
      const unsigned long long o = __shfl_xor(key, j);
      const bool takemin = (((lane & j) == 0) == ((lane & k) == 0));
      key = takemin ? (key < o ? key : o) : (key > o ? key : o);
    }
  }
  return key;
}
__device__ __forceinline__ float bsortf(float v, int lane) {
#pragma unroll
  for (int k = 2; k <= 64; k <<= 1) {
#pragma unroll
    for (int j = k >> 1; j > 0; j >>= 1) {
      const float o = __shfl_xor(v, j);
      const bool takemin = (((lane & j) == 0) == ((lane & k) == 0));
      v = takemin ? fminf(v, o) : fmaxf(v, o);
    }
  }
  return v;
}

// Kernel 0: per batch, bitonic-sort points by x; emit sorted float4
// {x,y,z,|p|^2}, orig-index array, and per-chunk x-bounds.
__global__ __launch_bounds__(1024) void sort_k(
    const float* __restrict__ pts, float4* __restrict__ PS,
    int* __restrict__ IS, float2* __restrict__ CB)
{
  __shared__ unsigned long long KEYS[NN];   // 64 KiB
  const int b = blockIdx.x;
  const float* px = pts + (size_t)b * (3 * NN);

  for (int i = threadIdx.x; i < NN; i += 1024)
    KEYS[i] = ((unsigned long long)encf(px[i]) << 32) | (unsigned)i;
  __syncthreads();

  for (int k = 2; k <= NN; k <<= 1) {
    for (int j = k >> 1; j > 0; j >>= 1) {
      for (int p = threadIdx.x; p < NN / 2; p += 1024) {
        const int i1 = ((p & ~(j - 1)) << 1) | (p & (j - 1));
        const int i2 = i1 | j;
        const bool up = (i1 & k) == 0;
        const unsigned long long a = KEYS[i1], c = KEYS[i2];
        if (up ? (a > c) : (a < c)) { KEYS[i1] = c; KEYS[i2] = a; }
      }
      __syncthreads();
    }
  }

  for (int i = threadIdx.x; i < NN; i += 1024) {
    const unsigned long long key = KEYS[i];
    const int oi = (int)(unsigned)(key & 0xffffffffu);
    const float a = px[oi], c = px[NN + oi], e = px[2 * NN + oi];
    PS[(size_t)b * NN + i] = make_float4(a, c, e,
                                         fmaf(e, e, fmaf(c, c, a * a)));
    IS[(size_t)b * NN + i] = oi;
    const float xs = decf((unsigned)(key >> 32));
    if ((i & 63) == 0)  CB[(size_t)b * NCH + (i >> 6)].x = xs;
    if ((i & 63) == 63) CB[(size_t)b * NCH + (i >> 6)].y = xs;
  }
}

// Kernel 1: per (b,n) point, per o=lane:
//   y1[row,o] = sum_d W[o,d]      * x[b,d,n]
//   cc[row,o] = sum_d (W[o,D+d]-W[o,d]) * x[b,d,n]
__global__ __launch_bounds__(256) void precomp_k(
    const float* __restrict__ x, const float* __restrict__ W,
    float* __restrict__ y1, float* __restrict__ cc)
{
  const int lane = threadIdx.x & 63;
  const int wid  = blockIdx.x * (blockDim.x >> 6) + (threadIdx.x >> 6);
  const int nw   = (gridDim.x * blockDim.x) >> 6;

  float w1[DD], wd[DD];
#pragma unroll
  for (int d = 0; d < DD; ++d) {
    float a  = W[lane * (2 * DD) + d];
    float b2 = W[lane * (2 * DD) + DD + d];
    w1[d] = a;
    wd[d] = b2 - a;
  }

  for (int row = wid; row < BB * NN; row += nw) {
    const float* xp = x + ((size_t)(row >> 13)) * (DD * NN) + (row & (NN - 1));
    float a1 = 0.f, a2 = 0.f;
#pragma unroll
    for (int d = 0; d < DD; ++d) {
      float xv = xp[(size_t)d * NN];
      a1 = fmaf(w1[d], xv, a1);
      a2 = fmaf(wd[d], xv, a2);
    }
    y1[(size_t)row * OO + lane] = a1;
    cc[(size_t)row * OO + lane] = a2;
  }
}

// Kernel 2: x-window-pruned exact KNN top-32 + fused edge-conv.
// 2048 blocks x 256 threads; wave = 4 consecutive SORTED queries. Certified
// chain: thr_a (64 sorted-neighbors) -> window_a -> pass-1 lane-min -> thr_b
// (rank ~44 bound) -> window_b -> buffered admission (+compaction). Reads
// sorted points straight from global (L2-resident); no __syncthreads.
__global__ __launch_bounds__(256, 8) void knn_k(
    const float4* __restrict__ PS, const int* __restrict__ IS,
    const float2* __restrict__ CB, const float* __restrict__ y1,
    const float* __restrict__ cc, float* __restrict__ out)
{
  __shared__ unsigned long long BUF[QB][64];   // 8 KiB
  const int b    = blockIdx.x >> 9;            // 512 blocks per batch
  const int qblk = blockIdx.x & 511;
  const int lane = threadIdx.x & 63;
  const int wv   = threadIdx.x >> 6;           // 0..3
  const int i0   = qblk * QB + wv * QPW;       // sorted query base

  const float4* ps = PS + (size_t)b * NN;
  const float2* cb = CB + (size_t)b * NCH;
  const int*    is = IS + (size_t)b * NN;

  float qx[QPW], q2[QPW], m2x[QPW], m2y[QPW], m2z[QPW], thr[QPW];
#pragma unroll
  for (int qq = 0; qq < QPW; ++qq) {
    const float4 qf = ps[i0 + qq];             // wave-uniform broadcast load
    qx[qq] = qf.x; q2[qq] = qf.w;
    m2x[qq] = -2.f * qf.x; m2y[qq] = -2.f * qf.y; m2z[qq] = -2.f * qf.z;
  }

  // ---- warm-up: 64 sorted-adjacent candidates -> certified thr_a ---------
#pragma unroll
  for (int qq = 0; qq < QPW; ++qq) {
    int c0 = i0 + qq - 32;
    c0 = c0 < 0 ? 0 : (c0 > NN - 64 ? NN - 64 : c0);
    const float4 p = ps[c0 + lane];
    float t = fmaf(p.x, m2x[qq], p.w);
    t = fmaf(p.y, m2y[qq], t);
    t = fmaf(p.z, m2z[qq], t);
    const float s = bsortf(t, lane);
    thr[qq] = ulp_up(__uint_as_float((unsigned)__builtin_amdgcn_readlane(
        (int)__float_as_uint(s), 31)));
  }

  // ---- window from current thresholds (certified, margin >> fp slop) -----
  int jlo, jhi;
  {
    float wlo = INFINITY, whi = -INFINITY;
#pragma unroll
    for (int qq = 0; qq < QPW; ++qq) {
      const float r = sqrtf(fmaxf(thr[qq] + q2[qq], 0.f) + 1e-4f);
      wlo = fminf(wlo, qx[qq] - r);
      whi = fmaxf(whi, qx[qq] + r);
    }
    const float2 c1 = cb[lane];
    const float2 c2 = cb[64 + lane];
    const unsigned long long m1 = __ballot(!(c1.y < wlo || c1.x > whi));
    const unsigned long long m2 = __ballot(!(c2.y < wlo || c2.x > whi));
    jlo = m1 ? (__ffsll((long long)m1) - 1)
             : (64 + __ffsll((long long)m2) - 1);
    jhi = m2 ? (127 - __clzll((long long)m2)) : (63 - __clzll((long long)m1));
  }

  // ---- pass 1 over window_a: lane-min -> thr_b (rank ~44 certified) ------
  float minv[QPW] = {INFINITY, INFINITY, INFINITY, INFINITY};
#pragma unroll 1
  for (int j = jlo; j <= jhi; ++j) {
    const float4 p = ps[j * 64 + lane];
#pragma unroll
    for (int qq = 0; qq < QPW; ++qq) {
      float t = fmaf(p.x, m2x[qq], p.w);
      t = fmaf(p.y, m2y[qq], t);
      t = fmaf(p.z, m2z[qq], t);
      minv[qq] = fminf(minv[qq], t);
    }
  }
#pragma unroll
  for (int qq = 0; qq < QPW; ++qq) {
    const float s = bsortf(minv[qq], lane);
    const float t31 = ulp_up(__uint_as_float(
        (unsigned)__builtin_amdgcn_readlane((int)__float_as_uint(s), 31)));
    thr[qq] = fminf(thr[qq], t31);
  }

  // ---- window_b + pass 2: buffered admissions (exact, stable) ------------
  int cnt[QPW] = {0, 0, 0, 0};
  {
    float wlo = INFINITY, whi = -INFINITY;
#pragma unroll
    for (int qq = 0; qq < QPW; ++qq) {
      const float r = sqrtf(fmaxf(thr[qq] + q2[qq], 0.f) + 1e-4f);
      wlo = fminf(wlo, qx[qq] - r);
      whi = fmaxf(whi, qx[qq] + r);
    }
    const float2 c1 = cb[lane];
    const float2 c2 = cb[64 + lane];
    const unsigned long long m1 = __ballot(!(c1.y < wlo || c1.x > whi));
    const unsigned long long m2 = __ballot(!(c2.y < wlo || c2.x > whi));
    jlo = m1 ? (__ffsll((long long)m1) - 1)
             : (64 + __ffsll((long long)m2) - 1);
    jhi = m2 ? (127 - __clzll((long long)m2)) : (63 - __clzll((long long)m1));
  }

#pragma unroll 1
  for (int j = jlo; j <= jhi; ++j) {
    const float4 p = ps[j * 64 + lane];
    float t[QPW]; unsigned long long bq[QPW];
#pragma unroll
    for (int qq = 0; qq < QPW; ++qq) {
      float tt = fmaf(p.x, m2x[qq], p.w);
      tt = fmaf(p.y, m2y[qq], tt);
      tt = fmaf(p.z, m2z[qq], tt);
      t[qq] = tt;
      bq[qq] = __ballot(tt < thr[qq]);
    }
    if ((bq[0] | bq[1]) | (bq[2] | bq[3])) {
      const int io = is[j * 64 + lane];      // original index (stable key)
#pragma unroll
      for (int qq = 0; qq < QPW; ++qq) {
        if (bq[qq]) {
          const int nadm = __popcll(bq[qq]);
          if (cnt[qq] + nadm <= 64) {
            if (t[qq] < thr[qq]) {
              const int pos = cnt[qq] + __builtin_amdgcn_mbcnt_hi(
                  (unsigned)(bq[qq] >> 32),
                  __builtin_amdgcn_mbcnt_lo((unsigned)bq[qq], 0));
              BUF[wv * QPW + qq][pos] =
                  ((unsigned long long)encf(t[qq]) << 32) | (unsigned)io;
            }
            cnt[qq] += nadm;
          } else {
            // rare: serial append with compact-on-full (certified exact)
            unsigned long long rem = bq[qq];
            while (rem) {
              if (cnt[qq] == 64) {
                unsigned long long ck = BUF[wv * QPW + qq][lane];
                ck = bsort64(ck, lane);
                BUF[wv * QPW + qq][lane] = ck;
                cnt[qq] = 32;
                thr[qq] = ulp_up(decf((unsigned)__builtin_amdgcn_readlane(
                    (int)(unsigned)(ck >> 32), 31)));
                rem &= __ballot(t[qq] < thr[qq]);
                continue;
              }
              const int src = __ffsll((long long)rem) - 1;
              rem &= rem - 1;
              if (lane == src)
                BUF[wv * QPW + qq][cnt[qq]] =
                    ((unsigned long long)encf(t[qq]) << 32) | (unsigned)io;
              cnt[qq] += 1;
            }
          }
        }
      }
    }
  }

  // ---- selection (bitonic) + fused conv epilogue -------------------------
#pragma unroll 1
  for (int qq = 0; qq < QPW; ++qq) {
    unsigned long long key = (lane < cnt[qq]) ? BUF[wv * QPW + qq][lane]
                                              : ~0ull;
    key = bsort64(key, lane);          // lanes 0..31: stable top-32 in order
    const int li = (int)(unsigned)(key & 0xffffffffu);

    const int n = is[i0 + qq];         // original query column
    const size_t rq = (size_t)b * NN + n;
    const float cv = cc[rq * OO + lane];
    float acc = 0.f;
#pragma unroll
    for (int k = 0; k < KK; ++k) {
      const int mk = __builtin_amdgcn_readlane(li, k);
      const float tt = y1[((size_t)b * NN + mk) * OO + lane] + cv;
      acc += (tt >= 0.f) ? tt : 0.2f * tt;
    }
    out[(size_t)b * (OO * NN) + (size_t)lane * NN + n] = acc * (1.f / 32.f);
  }
}

extern "C" void kernel_launch(void* const* d_in, const int* in_sizes, int n_in,
                              void* d_out, int out_size, void* d_ws, size_t ws_size,
                              hipStream_t stream) {
  const float* points = (const float*)d_in[0];
  const float* x      = (const float*)d_in[1];
  const float* W      = (const float*)d_in[2];
  float* out = (float*)d_out;

  float*  y1 = (float*)d_ws;                        // 8 MB
  float*  cc = y1 + (size_t)BB * NN * OO;           // 8 MB
  float4* PS = (float4*)(cc + (size_t)BB * NN * OO); // 512 KB
  int*    IS = (int*)(PS + (size_t)BB * NN);        // 128 KB
  float2* CB = (float2*)(IS + (size_t)BB * NN);     // 4 KB

  hipLaunchKernelGGL(sort_k, dim3(BB), dim3(1024), 0, stream,
                     points, PS, IS, CB);
  hipLaunchKernelGGL(precomp_k, dim3(2048), dim3(256), 0, stream, x, W, y1, cc);
  hipLaunchKernelGGL(knn_k, dim3(BB * NN / QB), dim3(256), 0, stream,
                     PS, IS, CB, y1, cc, out);
}

// Round 10
// 242.302 us; speedup vs baseline: 1.2552x; 1.2552x over previous
//
#include <hip/hip_runtime.h>
#include <math.h>

#define BB 4
#define NN 8192
#define DD 16
#define KK 32
#define OO 64
#define QPW 4        // queries per wave
#define QB  16       // queries per block (256 threads = 4 waves)
#define NCH (NN/64)  // 128 chunks of 64 sorted points
#define NBIN 256
#define XLO (-6.0f)
#define XHI (6.0f)

// ---- sortable-float helpers (monotone bijection float -> uint32) ----------
__device__ __forceinline__ unsigned encf(float f) {
  unsigned u = __float_as_uint(f);
  return ((int)u >= 0) ? (u | 0x80000000u) : ~u;
}
__device__ __forceinline__ float decf(unsigned s) {
  unsigned u = (s & 0x80000000u) ? (s & 0x7fffffffu) : ~s;
  return __uint_as_float(u);
}
__device__ __forceinline__ float ulp_up(float f) {
  unsigned u = __float_as_uint(f);
  u = ((u << 1) == 0u) ? 1u : (((int)u >= 0) ? u + 1u : u - 1u);
  return __uint_as_float(u);
}
// ---- 64-lane bitonic sorts (ascending) ------------------------------------
__device__ __forceinline__ unsigned long long bsort64(unsigned long long key,
                                                      int lane) {
#pragma unroll
  for (int k = 2; k <= 64; k <<= 1) {
#pragma unroll
    for (int j = k >> 1; j > 0; j >>= 1) {
      const unsigned long long o = __shfl_xor(key, j);
      const bool takemin = (((lane & j) == 0) == ((lane & k) == 0));
      key = takemin ? (key < o ? key : o) : (key > o ? key : o);
    }
  }
  return key;
}
__device__ __forceinline__ float bsortf(float v, int lane) {
#pragma unroll
  for (int k = 2; k <= 64; k <<= 1) {
#pragma unroll
    for (int j = k >> 1; j > 0; j >>= 1) {
      const float o = __shfl_xor(v, j);
      const bool takemin = (((lane & j) == 0) == ((lane & k) == 0));
      v = takemin ? fminf(v, o) : fmaxf(v, o);
    }
  }
  return v;
}

// Kernel A (1 block): per-batch 256-bin histogram of x, exclusive scan,
// init bin cursors and chunk-bound arrays. BB*NBIN == 1024 == blockDim.
__global__ __launch_bounds__(1024) void hist_scan_k(
    const float* __restrict__ pts, int* __restrict__ binStart,
    int* __restrict__ binCur, unsigned* __restrict__ CBminE,
    unsigned* __restrict__ CBmaxE)
{
  __shared__ int h[BB * NBIN];
  __shared__ int s[BB * NBIN];
  const int tid = threadIdx.x;
  h[tid] = 0;
  __syncthreads();
  for (int i = tid; i < BB * NN; i += 1024) {
    const int b = i >> 13, n = i & (NN - 1);
    const float xv = pts[(size_t)b * 3 * NN + n];
    int bin = (int)((xv - XLO) * ((float)NBIN / (XHI - XLO)));
    bin = bin < 0 ? 0 : (bin > NBIN - 1 ? NBIN - 1 : bin);
    atomicAdd(&h[b * NBIN + bin], 1);
  }
  __syncthreads();
  s[tid] = h[tid];
  __syncthreads();
  const int seg = tid & (NBIN - 1);
  for (int off = 1; off < NBIN; off <<= 1) {
    const int add = (seg >= off) ? s[tid - off] : 0;
    __syncthreads();
    s[tid] += add;
    __syncthreads();
  }
  const int excl = s[tid] - h[tid];
  binStart[tid] = excl;
  binCur[tid]   = excl;
  for (int i = tid; i < BB * NCH; i += 1024) {
    CBminE[i] = 0xFFFFFFFFu;
    CBmaxE[i] = 0u;
  }
}

// Kernel B: scatter points into bin-sorted order; emit float4 {x,y,z,|p|^2},
// sorted->orig (IS), orig->sorted (INV), and per-chunk x-bounds (atomics).
__global__ __launch_bounds__(256) void scatter_k(
    const float* __restrict__ pts, int* __restrict__ binCur,
    float4* __restrict__ PS, int* __restrict__ IS, int* __restrict__ INV,
    unsigned* __restrict__ CBminE, unsigned* __restrict__ CBmaxE)
{
  const int i = blockIdx.x * 256 + threadIdx.x;
  if (i >= BB * NN) return;
  const int b = i >> 13, n = i & (NN - 1);
  const float* px = pts + (size_t)b * 3 * NN;
  const float a = px[n], c = px[NN + n], e = px[2 * NN + n];
  int bin = (int)((a - XLO) * ((float)NBIN / (XHI - XLO)));
  bin = bin < 0 ? 0 : (bin > NBIN - 1 ? NBIN - 1 : bin);
  const int pos = atomicAdd(&binCur[b * NBIN + bin], 1);
  PS[(size_t)b * NN + pos] = make_float4(a, c, e,
                                         fmaf(e, e, fmaf(c, c, a * a)));
  IS[(size_t)b * NN + pos] = n;
  INV[(size_t)b * NN + n]  = pos;
  const int ch = b * NCH + (pos >> 6);
  const unsigned ex = encf(a);
  atomicMin(&CBminE[ch], ex);
  atomicMax(&CBmaxE[ch], ex);
}

// Kernel 1: per (b,n) point, per o=lane:
//   y1[row,o] = sum_d W[o,d]      * x[b,d,n]
//   cc[row,o] = sum_d (W[o,D+d]-W[o,d]) * x[b,d,n]
__global__ __launch_bounds__(256) void precomp_k(
    const float* __restrict__ x, const float* __restrict__ W,
    float* __restrict__ y1, float* __restrict__ cc)
{
  const int lane = threadIdx.x & 63;
  const int wid  = blockIdx.x * (blockDim.x >> 6) + (threadIdx.x >> 6);
  const int nw   = (gridDim.x * blockDim.x) >> 6;

  float w1[DD], wd[DD];
#pragma unroll
  for (int d = 0; d < DD; ++d) {
    float a  = W[lane * (2 * DD) + d];
    float b2 = W[lane * (2 * DD) + DD + d];
    w1[d] = a;
    wd[d] = b2 - a;
  }

  for (int row = wid; row < BB * NN; row += nw) {
    const float* xp = x + ((size_t)(row >> 13)) * (DD * NN) + (row & (NN - 1));
    float a1 = 0.f, a2 = 0.f;
#pragma unroll
    for (int d = 0; d < DD; ++d) {
      float xv = xp[(size_t)d * NN];
      a1 = fmaf(w1[d], xv, a1);
      a2 = fmaf(wd[d], xv, a2);
    }
    y1[(size_t)row * OO + lane] = a1;
    cc[(size_t)row * OO + lane] = a2;
  }
}

// Kernel 2: x-window-pruned exact KNN top-32 + fused edge-conv.
// 2048 blocks x 256 threads; wave = 4 adjacent BIN-SORTED queries.
// Batch<->XCD swizzle: batch = (bid&7)>>1 so each batch's y1/cc stay in
// 2 XCDs' L2. Output written COALESCED to OUT_S[b][i_sorted][o]; a separate
// permute kernel scatters to the reference layout.
__global__ __launch_bounds__(256, 8) void knn_k(
    const float4* __restrict__ PS, const int* __restrict__ IS,
    const unsigned* __restrict__ CBminE, const unsigned* __restrict__ CBmaxE,
    const float* __restrict__ y1, const float* __restrict__ cc,
    float* __restrict__ OUT_S)
{
  __shared__ unsigned long long BUF[QB][64];   // 8 KiB
  const int bid  = blockIdx.x;
  const int b    = (bid & 7) >> 1;             // 2 XCD slots per batch
  const int qblk = (bid >> 3) * 2 + (bid & 1); // 0..511 within batch
  const int lane = threadIdx.x & 63;
  const int wv   = threadIdx.x >> 6;           // 0..3
  const int i0   = qblk * QB + wv * QPW;       // sorted query base

  const float4* ps = PS + (size_t)b * NN;
  const int*    is = IS + (size_t)b * NN;

  // chunk x-bounds, hoisted (chunks 0..127 across two lane-groups)
  const float c1lo = decf(CBminE[b * NCH + lane]);
  const float c1hi = decf(CBmaxE[b * NCH + lane]);
  const float c2lo = decf(CBminE[b * NCH + 64 + lane]);
  const float c2hi = decf(CBmaxE[b * NCH + 64 + lane]);

  float qx[QPW], q2[QPW], m2x[QPW], m2y[QPW], m2z[QPW], thr[QPW];
#pragma unroll
  for (int qq = 0; qq < QPW; ++qq) {
    const float4 qf = ps[i0 + qq];             // wave-uniform broadcast load
    qx[qq] = qf.x; q2[qq] = qf.w;
    m2x[qq] = -2.f * qf.x; m2y[qq] = -2.f * qf.y; m2z[qq] = -2.f * qf.z;
  }

  // ---- warm-up: 64 sorted-adjacent candidates -> certified thr_a ---------
#pragma unroll
  for (int qq = 0; qq < QPW; ++qq) {
    int c0 = i0 + qq - 32;
    c0 = c0 < 0 ? 0 : (c0 > NN - 64 ? NN - 64 : c0);
    const float4 p = ps[c0 + lane];
    float t = fmaf(p.x, m2x[qq], p.w);
    t = fmaf(p.y, m2y[qq], t);
    t = fmaf(p.z, m2z[qq], t);
    const float s = bsortf(t, lane);
    thr[qq] = ulp_up(__uint_as_float((unsigned)__builtin_amdgcn_readlane(
        (int)__float_as_uint(s), 31)));
  }

  // ---- window_a from thr_a (certified; margin >> fp slop) ----------------
  int jlo, jhi;
  {
    float wlo = INFINITY, whi = -INFINITY;
#pragma unroll
    for (int qq = 0; qq < QPW; ++qq) {
      const float r = sqrtf(fmaxf(thr[qq] + q2[qq], 0.f) + 1e-4f);
      wlo = fminf(wlo, qx[qq] - r);
      whi = fmaxf(whi, qx[qq] + r);
    }
    const unsigned long long m1 = __ballot(!(c1hi < wlo || c1lo > whi));
    const unsigned long long m2 = __ballot(!(c2hi < wlo || c2lo > whi));
    jlo = m1 ? (__ffsll((long long)m1) - 1)
             : (64 + __ffsll((long long)m2) - 1);
    jhi = m2 ? (127 - __clzll((long long)m2)) : (63 - __clzll((long long)m1));
  }

  // ---- pass 1 over window_a: lane-min -> thr_b (rank ~44 certified) ------
  float minv[QPW] = {INFINITY, INFINITY, INFINITY, INFINITY};
#pragma unroll 1
  for (int j = jlo; j <= jhi; ++j) {
    const float4 p = ps[j * 64 + lane];
#pragma unroll
    for (int qq = 0; qq < QPW; ++qq) {
      float t = fmaf(p.x, m2x[qq], p.w);
      t = fmaf(p.y, m2y[qq], t);
      t = fmaf(p.z, m2z[qq], t);
      minv[qq] = fminf(minv[qq], t);
    }
  }
#pragma unroll
  for (int qq = 0; qq < QPW; ++qq) {
    const float s = bsortf(minv[qq], lane);
    const float t31 = ulp_up(__uint_as_float(
        (unsigned)__builtin_amdgcn_readlane((int)__float_as_uint(s), 31)));
    thr[qq] = fminf(thr[qq], t31);
  }

  // ---- window_b + pass 2: buffered admissions (exact, stable) ------------
  int cnt[QPW] = {0, 0, 0, 0};
  {
    float wlo = INFINITY, whi = -INFINITY;
#pragma unroll
    for (int qq = 0; qq < QPW; ++qq) {
      const float r = sqrtf(fmaxf(thr[qq] + q2[qq], 0.f) + 1e-4f);
      wlo = fminf(wlo, qx[qq] - r);
      whi = fmaxf(whi, qx[qq] + r);
    }
    const unsigned long long m1 = __ballot(!(c1hi < wlo || c1lo > whi));
    const unsigned long long m2 = __ballot(!(c2hi < wlo || c2lo > whi));
    jlo = m1 ? (__ffsll((long long)m1) - 1)
             : (64 + __ffsll((long long)m2) - 1);
    jhi = m2 ? (127 - __clzll((long long)m2)) : (63 - __clzll((long long)m1));
  }

#pragma unroll 1
  for (int j = jlo; j <= jhi; ++j) {
    const float4 p = ps[j * 64 + lane];
    float t[QPW]; unsigned long long bq[QPW];
#pragma unroll
    for (int qq = 0; qq < QPW; ++qq) {
      float tt = fmaf(p.x, m2x[qq], p.w);
      tt = fmaf(p.y, m2y[qq], tt);
      tt = fmaf(p.z, m2z[qq], tt);
      t[qq] = tt;
      bq[qq] = __ballot(tt < thr[qq]);
    }
    if ((bq[0] | bq[1]) | (bq[2] | bq[3])) {
      const int io = is[j * 64 + lane];      // original index (stable key)
#pragma unroll
      for (int qq = 0; qq < QPW; ++qq) {
        if (bq[qq]) {
          const int nadm = __popcll(bq[qq]);
          if (cnt[qq] + nadm <= 64) {
            if (t[qq] < thr[qq]) {
              const int pos = cnt[qq] + __builtin_amdgcn_mbcnt_hi(
                  (unsigned)(bq[qq] >> 32),
                  __builtin_amdgcn_mbcnt_lo((unsigned)bq[qq], 0));
              BUF[wv * QPW + qq][pos] =
                  ((unsigned long long)encf(t[qq]) << 32) | (unsigned)io;
            }
            cnt[qq] += nadm;
          } else {
            // rare: serial append with compact-on-full (certified exact)
            unsigned long long rem = bq[qq];
            while (rem) {
              if (cnt[qq] == 64) {
                unsigned long long ck = BUF[wv * QPW + qq][lane];
                ck = bsort64(ck, lane);
                BUF[wv * QPW + qq][lane] = ck;
                cnt[qq] = 32;
                thr[qq] = ulp_up(decf((unsigned)__builtin_amdgcn_readlane(
                    (int)(unsigned)(ck >> 32), 31)));
                rem &= __ballot(t[qq] < thr[qq]);
                continue;
              }
              const int src = __ffsll((long long)rem) - 1;
              rem &= rem - 1;
              if (lane == src)
                BUF[wv * QPW + qq][cnt[qq]] =
                    ((unsigned long long)encf(t[qq]) << 32) | (unsigned)io;
              cnt[qq] += 1;
            }
          }
        }
      }
    }
  }

  // ---- selection (bitonic) + fused conv epilogue (COALESCED out) ---------
#pragma unroll 1
  for (int qq = 0; qq < QPW; ++qq) {
    unsigned long long key = (lane < cnt[qq]) ? BUF[wv * QPW + qq][lane]
                                              : ~0ull;
    key = bsort64(key, lane);          // lanes 0..31: stable top-32 in order
    const int li = (int)(unsigned)(key & 0xffffffffu);

    const int n = is[i0 + qq];         // original query index (for cc)
    const float cv = cc[((size_t)b * NN + n) * OO + lane];
    float acc = 0.f;
#pragma unroll
    for (int k = 0; k < KK; ++k) {
      const int mk = __builtin_amdgcn_readlane(li, k);
      const float tt = y1[((size_t)b * NN + mk) * OO + lane] + cv;
      acc += (tt >= 0.f) ? tt : 0.2f * tt;
    }
    OUT_S[((size_t)b * NN + i0 + qq) * OO + lane] = acc * (1.f / 32.f);
  }
}

// Kernel 3: transpose/scatter OUT_S[b][i_sorted][o] -> out[b][o][n].
// Block = (b, 128 consecutive original n). Row reads 256 B; writes coalesced.
__global__ __launch_bounds__(256) void permute_k(
    const float* __restrict__ OUT_S, const int* __restrict__ INV,
    float* __restrict__ out)
{
  __shared__ float T[OO][129];        // ~32 KiB, stride 129 = conflict-free
  const int b    = blockIdx.x >> 6;   // 64 blocks per batch
  const int n0   = (blockIdx.x & 63) * 128;
  const int lane = threadIdx.x & 63;
  const int wv   = threadIdx.x >> 6;  // 0..3

#pragma unroll 1
  for (int i = wv * 32; i < wv * 32 + 32; ++i) {
    const int row = INV[(size_t)b * NN + n0 + i];
    T[lane][i] = OUT_S[((size_t)b * NN + row) * OO + lane];
  }
  __syncthreads();
#pragma unroll 1
  for (int o = wv * 16; o < wv * 16 + 16; ++o) {
    float* op = out + (size_t)b * OO * NN + (size_t)o * NN + n0;
    op[lane]      = T[o][lane];
    op[64 + lane] = T[o][64 + lane];
  }
}

extern "C" void kernel_launch(void* const* d_in, const int* in_sizes, int n_in,
                              void* d_out, int out_size, void* d_ws, size_t ws_size,
                              hipStream_t stream) {
  const float* points = (const float*)d_in[0];
  const float* x      = (const float*)d_in[1];
  const float* W      = (const float*)d_in[2];
  float* out = (float*)d_out;

  float*  y1   = (float*)d_ws;                         // 8 MB
  float*  cc   = y1 + (size_t)BB * NN * OO;            // 8 MB
  float*  OUTS = cc + (size_t)BB * NN * OO;            // 8 MB
  float4* PS   = (float4*)(OUTS + (size_t)BB * NN * OO); // 512 KB
  int*    IS   = (int*)(PS + (size_t)BB * NN);         // 128 KB
  int*    INV  = IS + (size_t)BB * NN;                 // 128 KB
  int*    binStart = INV + (size_t)BB * NN;            // 4 KB
  int*    binCur   = binStart + BB * NBIN;             // 4 KB
  unsigned* CBminE = (unsigned*)(binCur + BB * NBIN);  // 2 KB
  unsigned* CBmaxE = CBminE + BB * NCH;                // 2 KB

  hipLaunchKernelGGL(hist_scan_k, dim3(1), dim3(1024), 0, stream,
                     points, binStart, binCur, CBminE, CBmaxE);
  hipLaunchKernelGGL(scatter_k, dim3(BB * NN / 256), dim3(256), 0, stream,
                     points, binCur, PS, IS, INV, CBminE, CBmaxE);
  hipLaunchKernelGGL(precomp_k, dim3(2048), dim3(256), 0, stream, x, W, y1, cc);
  hipLaunchKernelGGL(knn_k, dim3(BB * NN / QB), dim3(256), 0, stream,
                     PS, IS, CBminE, CBmaxE, y1, cc, OUTS);
  hipLaunchKernelGGL(permute_k, dim3(BB * 64), dim3(256), 0, stream,
                     OUTS, INV, out);
}